// Round 4
// baseline (169.539 us; speedup 1.0000x reference)
//
#include <hip/hip_runtime.h>
#include <hip/hip_bf16.h>
#include <math.h>

#define NB 256
#define NL 256
#define NH 128
#define NK 8

typedef __attribute__((ext_vector_type(8))) short bf16x8;
typedef __attribute__((ext_vector_type(4))) float f32x4;

static __device__ __forceinline__ short f2bf(float x) {
    __hip_bfloat16 b = __float2bfloat16(x);
    return *reinterpret_cast<short*>(&b);
}
static __device__ __forceinline__ float bf2f(short s) {
    __hip_bfloat16 b = *reinterpret_cast<__hip_bfloat16*>(&s);
    return __bfloat162float(b);
}
static __device__ __forceinline__ void split8(const float4 a, const float4 b,
                                              bf16x8& hi, bf16x8& lo) {
    const float x[8] = {a.x, a.y, a.z, a.w, b.x, b.y, b.z, b.w};
#pragma unroll
    for (int j = 0; j < 8; ++j) {
        const short h = f2bf(x[j]);
        hi[j] = h;
        lo[j] = f2bf(x[j] - bf2f(h));
    }
}

// e-tile LDS swizzle: XOR h-bits [6:2] with (l&31)
#define SWZ(l, h) ((h) ^ (((l) & 31) << 2))

// ---------------------------------------------------------------------------
// Setup: split W into bf16 hi/lo, plus transposed copies. 16384 elements.
// ---------------------------------------------------------------------------
__global__ __launch_bounds__(256) void setup_w_kernel(const float* __restrict__ W,
                                                      short* __restrict__ whi,
                                                      short* __restrict__ wlo,
                                                      short* __restrict__ wthi,
                                                      short* __restrict__ wtlo) {
    const int id = blockIdx.x * 256 + threadIdx.x;   // h*128 + j
    const int h = id >> 7, j = id & 127;
    const float w = W[id];
    const short hi = f2bf(w);
    const short lo = f2bf(w - bf2f(hi));
    whi[id] = hi;
    wlo[id] = lo;
    wthi[j * 128 + h] = hi;
    wtlo[j * 128 + h] = lo;
}

// ---------------------------------------------------------------------------
// Fused per-batch kernel: 256 blocks x 512 threads (8 waves). e_b LDS-resident.
// ---------------------------------------------------------------------------
__global__ __launch_bounds__(512) void fused_kernel(const float* __restrict__ e,
                                                    const float* __restrict__ b_init,
                                                    const short* __restrict__ whi,
                                                    const short* __restrict__ wlo,
                                                    const short* __restrict__ wthi,
                                                    const short* __restrict__ wtlo,
                                                    float* __restrict__ out) {
    const int b = blockIdx.x;
    const int t = threadIdx.x;
    const int lane = t & 63, wv = t >> 6;
    const int l16 = lane & 15, grp = lane >> 4;

    __shared__ __align__(16) float eb[NL * NH];        // 128 KB, swizzled
    __shared__ float logits[NK * NL];                  // 8 KB
    __shared__ float cbuf[NK * NL];                    // 8 KB
    __shared__ __align__(16) float mcap[NK * 132];     // 4.2 KB  (m, then g, then mu)
    __shared__ __align__(16) float capb[NK * 132];     // 4.2 KB
    __shared__ float enl[NL];                          // 1 KB
    __shared__ float nrm[NK], denomv[NK], svals[NK], strv[NK], Ps[28];

    const float* ebg = e + (size_t)b * (NL * NH);

    // --- stage e (swizzled) + logits ---
#pragma unroll
    for (int rep = 0; rep < 16; ++rep) {
        const int idx4 = rep * 512 + t;
        const int l = idx4 >> 5, h4 = (idx4 & 31) << 2;
        const float4 v = *(const float4*)&ebg[l * 128 + h4];
        *(float4*)&eb[l * 128 + SWZ(l, h4)] = v;
    }
#pragma unroll
    for (int rep = 0; rep < 4; ++rep)
        logits[rep * 512 + t] = b_init[(size_t)b * 2048 + rep * 512 + t];

    // --- preload W fragments (this wave's output-col block nf = wv) ---
    bf16x8 fWhi[4], fWlo[4], fThi[4], fTlo[4];
    {
        const int col = wv * 16 + l16;
#pragma unroll
        for (int ks = 0; ks < 4; ++ks) {
            const int off = col * 128 + ks * 32 + grp * 8;
            fWhi[ks] = *(const bf16x8*)&whi[off];
            fWlo[ks] = *(const bf16x8*)&wlo[off];
            fThi[ks] = *(const bf16x8*)&wthi[off];
            fTlo[ks] = *(const bf16x8*)&wtlo[off];
        }
    }
    __syncthreads();

    const int k = wv;  // each wave owns capsule k in most phases

    for (int iter = 0; iter < 3; ++iter) {
        // --- P1: softmax over L for capsule k ---
        {
            float v0 = logits[k * 256 + lane];
            float v1 = logits[k * 256 + 64 + lane];
            float v2 = logits[k * 256 + 128 + lane];
            float v3 = logits[k * 256 + 192 + lane];
            float m = fmaxf(fmaxf(v0, v1), fmaxf(v2, v3));
            for (int o = 32; o; o >>= 1) m = fmaxf(m, __shfl_xor(m, o));
            v0 = expf(v0 - m); v1 = expf(v1 - m); v2 = expf(v2 - m); v3 = expf(v3 - m);
            float s = v0 + v1 + v2 + v3;
            for (int o = 32; o; o >>= 1) s += __shfl_xor(s, o);
            const float inv = 1.0f / s;
            cbuf[k * 256 + lane] = v0 * inv;
            cbuf[k * 256 + 64 + lane] = v1 * inv;
            cbuf[k * 256 + 128 + lane] = v2 * inv;
            cbuf[k * 256 + 192 + lane] = v3 * inv;
        }
        __syncthreads();

        // --- P2: m[k][h] = sum_l c[k][l] * e[l][h]  (lane covers h=2*lane, +1) ---
        {
            float a0 = 0.f, a1 = 0.f;
            const int h2 = lane * 2;
#pragma unroll 4
            for (int l = 0; l < 256; ++l) {
                const float cl = cbuf[k * 256 + l];
                const float2 ev = *(const float2*)&eb[l * 128 + SWZ(l, h2)];
                a0 += cl * ev.x;
                a1 += cl * ev.y;
            }
            mcap[k * 132 + h2] = a0;
            mcap[k * 132 + h2 + 1] = a1;
        }
        __syncthreads();

        // --- P3: cap = W @ m  (split-bf16 MFMA; wave = output-col block nf) ---
        {
            f32x4 acc = (f32x4){0.f, 0.f, 0.f, 0.f};
#pragma unroll
            for (int ks = 0; ks < 4; ++ks) {
                const float4 a0 = *(const float4*)&mcap[(l16 & 7) * 132 + ks * 32 + grp * 8];
                const float4 a1 = *(const float4*)&mcap[(l16 & 7) * 132 + ks * 32 + grp * 8 + 4];
                bf16x8 ahi, alo;
                split8(a0, a1, ahi, alo);
                acc = __builtin_amdgcn_mfma_f32_16x16x32_bf16(ahi, fWhi[ks], acc, 0, 0, 0);
                acc = __builtin_amdgcn_mfma_f32_16x16x32_bf16(alo, fWhi[ks], acc, 0, 0, 0);
                acc = __builtin_amdgcn_mfma_f32_16x16x32_bf16(ahi, fWlo[ks], acc, 0, 0, 0);
            }
            if (grp < 2) {
#pragma unroll
                for (int r = 0; r < 4; ++r)
                    capb[(grp * 4 + r) * 132 + wv * 16 + l16] = acc[r];
            }
        }
        __syncthreads();

        // --- P4: squash ---
        {
            const float x0 = capb[k * 132 + lane], x1 = capb[k * 132 + 64 + lane];
            float s = x0 * x0 + x1 * x1;
            for (int o = 32; o; o >>= 1) s += __shfl_xor(s, o);
            if (lane == 0) nrm[k] = s;
        }
        __syncthreads();
        {
            const float n = nrm[k];
            const float sc = n / (1.0f + n) / sqrtf(n + 1e-9f);
            capb[k * 132 + lane] *= sc;
            capb[k * 132 + 64 + lane] *= sc;
        }
        __syncthreads();

        if (iter < 2) {
            // --- P5: g = W^T @ cap  (MFMA, into mcap region) ---
            {
                f32x4 acc = (f32x4){0.f, 0.f, 0.f, 0.f};
#pragma unroll
                for (int ks = 0; ks < 4; ++ks) {
                    const float4 a0 = *(const float4*)&capb[(l16 & 7) * 132 + ks * 32 + grp * 8];
                    const float4 a1 = *(const float4*)&capb[(l16 & 7) * 132 + ks * 32 + grp * 8 + 4];
                    bf16x8 ahi, alo;
                    split8(a0, a1, ahi, alo);
                    acc = __builtin_amdgcn_mfma_f32_16x16x32_bf16(ahi, fThi[ks], acc, 0, 0, 0);
                    acc = __builtin_amdgcn_mfma_f32_16x16x32_bf16(alo, fThi[ks], acc, 0, 0, 0);
                    acc = __builtin_amdgcn_mfma_f32_16x16x32_bf16(ahi, fTlo[ks], acc, 0, 0, 0);
                }
                if (grp < 2) {
#pragma unroll
                    for (int r = 0; r < 4; ++r)
                        mcap[(grp * 4 + r) * 132 + wv * 16 + l16] = acc[r];
                }
            }
            __syncthreads();

            // --- P6: logits[k][l] += e_l . g_k  (4 l's per lane) ---
#pragma unroll
            for (int qi = 0; qi < 4; ++qi) {
                const int l = qi * 64 + lane;
                float d = 0.f;
#pragma unroll
                for (int j0 = 0; j0 < 128; j0 += 4) {
                    const float4 ev = *(const float4*)&eb[l * 128 + SWZ(l, j0)];
                    const float4 gv = *(const float4*)&mcap[k * 132 + j0];
                    d += ev.x * gv.x + ev.y * gv.y + ev.z * gv.z + ev.w * gv.w;
                }
                logits[k * 256 + l] += d;
            }
            __syncthreads();
        }
    }

    // --- strengths from final squash norm: str = n/(1+n)*sqrt(n)/sqrt(n+eps9) ---
    if (t < 8) {
        const float n = nrm[t];
        strv[t] = n / (1.0f + n) * sqrtf(n) / sqrtf(n + 1e-9f);
    }

    // --- P8a: enl (waves 0-3) + denom (waves 4-7, two k's each) ---
    if (wv < 4) {
        const int l = wv * 64 + lane;
        float ss = 0.f;
#pragma unroll
        for (int j0 = 0; j0 < 128; j0 += 4) {
            const float4 ev = *(const float4*)&eb[l * 128 + SWZ(l, j0)];
            ss += ev.x * ev.x + ev.y * ev.y + ev.z * ev.z + ev.w * ev.w;
        }
        enl[l] = sqrtf(ss) + 1e-8f;
    } else {
#pragma unroll
        for (int rr = 0; rr < 2; ++rr) {
            const int kk = (wv - 4) + rr * 4;
            float s = cbuf[kk * 256 + lane] + cbuf[kk * 256 + 64 + lane] +
                      cbuf[kk * 256 + 128 + lane] + cbuf[kk * 256 + 192 + lane];
            for (int o = 32; o; o >>= 1) s += __shfl_xor(s, o);
            if (lane == 0) denomv[kk] = s + 1e-8f;
        }
    }
    __syncthreads();

    // --- P8b: mu_n in place on mcap (wave k) ---
    {
        const float dv = denomv[k];
        const float x0 = mcap[k * 132 + lane] / dv;
        const float x1 = mcap[k * 132 + 64 + lane] / dv;
        float s = x0 * x0 + x1 * x1;
        for (int o = 32; o; o >>= 1) s += __shfl_xor(s, o);
        const float nv = sqrtf(s) + 1e-8f;
        mcap[k * 132 + lane] = x0 / nv;
        mcap[k * 132 + 64 + lane] = x1 / nv;
    }
    __syncthreads();

    // --- P9: s[k] = sum_l c[k][l] * (e_l . mu_n_k) / enl[l] ---
    {
        float sacc = 0.f;
#pragma unroll
        for (int qi = 0; qi < 4; ++qi) {
            const int l = qi * 64 + lane;
            float d = 0.f;
#pragma unroll
            for (int j0 = 0; j0 < 128; j0 += 4) {
                const float4 ev = *(const float4*)&eb[l * 128 + SWZ(l, j0)];
                const float4 mv = *(const float4*)&mcap[k * 132 + j0];
                d += ev.x * mv.x + ev.y * mv.y + ev.z * mv.z + ev.w * mv.w;
            }
            sacc += cbuf[k * 256 + l] * (d / enl[l]);
        }
        for (int o = 32; o; o >>= 1) sacc += __shfl_xor(sacc, o);
        if (lane == 0) svals[k] = sacc;
    }

    // --- P10: Gram pairs (4 per wave) ---
#pragma unroll
    for (int pp = 0; pp < 4; ++pp) {
        const int p = wv + pp * 8;
        if (p < 28) {
            int i = 0, rem = p;
            while (rem >= 7 - i) { rem -= 7 - i; ++i; }
            const int j = i + 1 + rem;
            float v = mcap[i * 132 + lane] * mcap[j * 132 + lane] +
                      mcap[i * 132 + 64 + lane] * mcap[j * 132 + 64 + lane];
            for (int o = 32; o; o >>= 1) v += __shfl_xor(v, o);
            if (lane == 0) Ps[p] = v;
        }
    }
    __syncthreads();

    // --- P11: serial scoring ---
    if (t == 0) {
        int idx[8];
        for (int i = 0; i < 8; ++i) idx[i] = i;
        for (int a = 1; a < 8; ++a) {
            const int key = idx[a];
            const float kv = strv[key];
            int bb = a - 1;
            while (bb >= 0 && strv[idx[bb]] < kv) { idx[bb + 1] = idx[bb]; --bb; }
            idx[bb + 1] = key;
        }
        float best = -1e30f;
        int bestk = 2;
        float cons_sum = 0.f, pair_sum = 0.f;
        for (int kk = 1; kk <= 8; ++kk) {
            const int ni = idx[kk - 1];
            cons_sum += svals[ni];
            for (int a = 0; a < kk - 1; ++a) {
                const int ia = idx[a];
                const int lo = ia < ni ? ia : ni;
                const int hi2 = ia < ni ? ni : ia;
                const int off0 = lo * 7 - lo * (lo - 1) / 2;
                pair_sum += Ps[off0 + hi2 - lo - 1];
            }
            if (kk >= 2) {
                const float cons = cons_sum / (kk * 256.0f);
                const float divv = 1.0f - (2.0f / (kk * (kk - 1))) * pair_sum;
                const float score = 0.5f * cons + 0.5f * divv;
                out[256 + b * 7 + (kk - 2)] = score;
                if (score > best) { best = score; bestk = kk; }
            }
        }
        out[b] = (float)bestk;
    }
}

// ---------------------------------------------------------------------------
extern "C" void kernel_launch(void* const* d_in, const int* in_sizes, int n_in,
                              void* d_out, int out_size, void* d_ws, size_t ws_size,
                              hipStream_t stream) {
    const float* e = (const float*)d_in[0];
    const float* W = (const float*)d_in[1];
    const float* b_init = (const float*)d_in[2];
    float* out = (float*)d_out;

    short* whi = (short*)d_ws;
    short* wlo = whi + 16384;
    short* wthi = wlo + 16384;
    short* wtlo = wthi + 16384;

    hipLaunchKernelGGL(setup_w_kernel, dim3(64), dim3(256), 0, stream, W, whi, wlo, wthi, wtlo);
    hipLaunchKernelGGL(fused_kernel, dim3(NB), dim3(512), 0, stream,
                       e, b_init, whi, wlo, wthi, wtlo, out);
}

// Round 6
// 64.447 us; speedup vs baseline: 2.6307x; 2.6307x over previous
//
#include <hip/hip_runtime.h>
#include <hip/hip_bf16.h>
#include <math.h>

#define NB 256
#define NL 256
#define NH 128
#define NK 8

typedef __attribute__((ext_vector_type(8))) short bf16x8;
typedef __attribute__((ext_vector_type(4))) float f32x4;

static __device__ __forceinline__ short f2bf(float x) {
    __hip_bfloat16 b = __float2bfloat16(x);
    return *reinterpret_cast<short*>(&b);
}
static __device__ __forceinline__ float bf2f(short s) {
    __hip_bfloat16 b = *reinterpret_cast<__hip_bfloat16*>(&s);
    return __bfloat162float(b);
}
static __device__ __forceinline__ void split8(const float4 a, const float4 b,
                                              bf16x8& hi, bf16x8& lo) {
    const float x[8] = {a.x, a.y, a.z, a.w, b.x, b.y, b.z, b.w};
#pragma unroll
    for (int j = 0; j < 8; ++j) {
        const short h = f2bf(x[j]);
        hi[j] = h;
        lo[j] = f2bf(x[j] - bf2f(h));
    }
}

// eb swizzle: XOR word bits [4:2] with ((l>>5)^l)&7  (preserves 16B blocks)
#define SWZ(l, w) ((w) ^ ((((((l) >> 5)) ^ (l)) & 7) << 2))
// ct layout: 8 c-values per l, bank-spread across l-groups of 32
#define CB(l) ((l) * 12 + (((l) >> 5) << 2))

// ---------------------------------------------------------------------------
__global__ __launch_bounds__(256) void setup_w_kernel(const float* __restrict__ W,
                                                      short* __restrict__ whi,
                                                      short* __restrict__ wlo,
                                                      short* __restrict__ wthi,
                                                      short* __restrict__ wtlo) {
    const int id = blockIdx.x * 256 + threadIdx.x;   // h*128 + j
    const int h = id >> 7, j = id & 127;
    const float w = W[id];
    const short hi = f2bf(w);
    const short lo = f2bf(w - bf2f(hi));
    whi[id] = hi;
    wlo[id] = lo;
    wthi[j * 128 + h] = hi;
    wtlo[j * 128 + h] = lo;
}

// ---------------------------------------------------------------------------
// Fused per-batch kernel: 256 blocks x 1024 threads (16 waves), e LDS-resident.
// ---------------------------------------------------------------------------
__global__ __launch_bounds__(1024) void fused_kernel(const float* __restrict__ e,
                                                     const float* __restrict__ b_init,
                                                     const short* __restrict__ whi,
                                                     const short* __restrict__ wlo,
                                                     const short* __restrict__ wthi,
                                                     const short* __restrict__ wtlo,
                                                     float* __restrict__ out) {
    const int b = blockIdx.x;
    const int t = threadIdx.x;
    const int lane = t & 63, wv = t >> 6;
    const int l16 = lane & 15, grp = lane >> 4;

    __shared__ __align__(16) float eb[NL * NH];     // 128 KB (swizzled)
    __shared__ float logits[NK * NL];               // 8 KB
    __shared__ __align__(16) float ct[3096];        // 12.1 KB  c transposed
    __shared__ __align__(16) float mcap[NK * 132];  // 4.1 KB  (m -> g -> mu_n)
    __shared__ __align__(16) float capb[NK * 132];  // 4.1 KB  (cap)
    __shared__ float enl[NL];                       // 1 KB
    __shared__ float wavePart[16 * 8];              // 512 B
    __shared__ float svals[NK], strv[NK], Ps[28];

    const float* ebg = e + (size_t)b * (NL * NH);

    // --- stage e (swizzled) + logits ---
#pragma unroll
    for (int rep = 0; rep < 8; ++rep) {
        const int idx4 = rep * 1024 + t;
        const int l = idx4 >> 5, w4 = (idx4 & 31) << 2;
        const float4 v = *(const float4*)&ebg[l * 128 + w4];
        *(float4*)&eb[l * 128 + SWZ(l, w4)] = v;
    }
    logits[t] = b_init[(size_t)b * 2048 + t];
    logits[t + 1024] = b_init[(size_t)b * 2048 + t + 1024];
    __syncthreads();

    // --- e row norms (once); consumed only at P9, after many barriers ---
    {
        const int l = t >> 2, q = t & 3;
        float ss = 0.f;
#pragma unroll
        for (int jj = 0; jj < 8; ++jj) {
            const float4 ev = *(const float4*)&eb[l * 128 + SWZ(l, q * 32 + jj * 4)];
            ss += ev.x * ev.x + ev.y * ev.y + ev.z * ev.z + ev.w * ev.w;
        }
        ss += __shfl_xor(ss, 1);
        ss += __shfl_xor(ss, 2);
        if (q == 0) enl[l] = sqrtf(ss) + 1e-8f;
    }

    for (int iter = 0; iter < 3; ++iter) {
        // --- P1: softmax over L; wave pair per capsule ---
        {
            const int k = wv & 7, half = wv >> 3;
            float v0 = logits[k * 256 + lane];
            float v1 = logits[k * 256 + 64 + lane];
            float v2 = logits[k * 256 + 128 + lane];
            float v3 = logits[k * 256 + 192 + lane];
            float m = fmaxf(fmaxf(v0, v1), fmaxf(v2, v3));
#pragma unroll
            for (int o = 32; o; o >>= 1) m = fmaxf(m, __shfl_xor(m, o));
            v0 = expf(v0 - m); v1 = expf(v1 - m); v2 = expf(v2 - m); v3 = expf(v3 - m);
            float s = v0 + v1 + v2 + v3;
#pragma unroll
            for (int o = 32; o; o >>= 1) s += __shfl_xor(s, o);
            const float inv = 1.0f / s;
            const float a = half ? v2 : v0;
            const float bq = half ? v3 : v1;
            const int lbase = half * 128;
            ct[CB(lbase + lane) + k] = a * inv;
            ct[CB(lbase + 64 + lane) + k] = bq * inv;
        }
        __syncthreads();

        // --- P2: m[k][h] = sum_l c[k][l]*e[l][h]; (h,g) = (t>>3, t&7) ---
        {
            const int h = t >> 3, g = t & 7;
            float acc[8] = {0, 0, 0, 0, 0, 0, 0, 0};
#pragma unroll 4
            for (int i = 0; i < 32; ++i) {
                const int l = g * 32 + i;
                const float4 c0 = *(const float4*)&ct[CB(l)];
                const float4 c1 = *(const float4*)&ct[CB(l) + 4];
                const float ev = eb[l * 128 + SWZ(l, h)];
                acc[0] += c0.x * ev; acc[1] += c0.y * ev;
                acc[2] += c0.z * ev; acc[3] += c0.w * ev;
                acc[4] += c1.x * ev; acc[5] += c1.y * ev;
                acc[6] += c1.z * ev; acc[7] += c1.w * ev;
            }
#pragma unroll
            for (int k = 0; k < 8; ++k) {
                acc[k] += __shfl_xor(acc[k], 1);
                acc[k] += __shfl_xor(acc[k], 2);
                acc[k] += __shfl_xor(acc[k], 4);
            }
            if (g == 0) {
#pragma unroll
                for (int k = 0; k < 8; ++k) mcap[k * 132 + h] = acc[k];
            }
        }
        __syncthreads();

        // --- P3: cap = m @ W^T (split-bf16 MFMA, waves 0-7, W frags from L2) ---
        if (wv < 8) {
            const int n0 = wv * 16;
            const int arow = (l16 & 7) * 132;
            const int kbase = grp * 8;
            f32x4 acc = (f32x4){0.f, 0.f, 0.f, 0.f};
            bf16x8 bh[4], bl[4];
#pragma unroll
            for (int ks = 0; ks < 4; ++ks) {
                bh[ks] = *(const bf16x8*)&whi[(n0 + l16) * 128 + ks * 32 + kbase];
                bl[ks] = *(const bf16x8*)&wlo[(n0 + l16) * 128 + ks * 32 + kbase];
            }
#pragma unroll
            for (int ks = 0; ks < 4; ++ks) {
                const float4 a0 = *(const float4*)&mcap[arow + ks * 32 + kbase];
                const float4 a1 = *(const float4*)&mcap[arow + ks * 32 + kbase + 4];
                bf16x8 ahi, alo;
                split8(a0, a1, ahi, alo);
                acc = __builtin_amdgcn_mfma_f32_16x16x32_bf16(ahi, bh[ks], acc, 0, 0, 0);
                acc = __builtin_amdgcn_mfma_f32_16x16x32_bf16(alo, bh[ks], acc, 0, 0, 0);
                acc = __builtin_amdgcn_mfma_f32_16x16x32_bf16(ahi, bl[ks], acc, 0, 0, 0);
            }
            if (grp < 2) {
#pragma unroll
                for (int r = 0; r < 4; ++r)
                    capb[(grp * 4 + r) * 132 + n0 + l16] = acc[r];
            }
        }
        __syncthreads();

        // --- P4: squash (wave-local) + strength on final iter ---
        if (wv < 8) {
            const int k = wv;
            const float x0 = capb[k * 132 + lane];
            const float x1 = capb[k * 132 + 64 + lane];
            float s = x0 * x0 + x1 * x1;
#pragma unroll
            for (int o = 32; o; o >>= 1) s += __shfl_xor(s, o);
            const float sc = s / (1.0f + s) / sqrtf(s + 1e-9f);
            capb[k * 132 + lane] = x0 * sc;
            capb[k * 132 + 64 + lane] = x1 * sc;
            if (iter == 2 && lane == 0)
                strv[k] = s / (1.0f + s) * sqrtf(s) / sqrtf(s + 1e-9f);
        }
        __syncthreads();

        if (iter < 2) {
            // --- P5: g = cap @ W (split-bf16 MFMA, waves 0-7) ---
            if (wv < 8) {
                const int n0 = wv * 16;
                const int arow = (l16 & 7) * 132;
                const int kbase = grp * 8;
                f32x4 acc = (f32x4){0.f, 0.f, 0.f, 0.f};
                bf16x8 bh[4], bl[4];
#pragma unroll
                for (int ks = 0; ks < 4; ++ks) {
                    bh[ks] = *(const bf16x8*)&wthi[(n0 + l16) * 128 + ks * 32 + kbase];
                    bl[ks] = *(const bf16x8*)&wtlo[(n0 + l16) * 128 + ks * 32 + kbase];
                }
#pragma unroll
                for (int ks = 0; ks < 4; ++ks) {
                    const float4 a0 = *(const float4*)&capb[arow + ks * 32 + kbase];
                    const float4 a1 = *(const float4*)&capb[arow + ks * 32 + kbase + 4];
                    bf16x8 ahi, alo;
                    split8(a0, a1, ahi, alo);
                    acc = __builtin_amdgcn_mfma_f32_16x16x32_bf16(ahi, bh[ks], acc, 0, 0, 0);
                    acc = __builtin_amdgcn_mfma_f32_16x16x32_bf16(alo, bh[ks], acc, 0, 0, 0);
                    acc = __builtin_amdgcn_mfma_f32_16x16x32_bf16(ahi, bl[ks], acc, 0, 0, 0);
                }
                if (grp < 2) {
#pragma unroll
                    for (int r = 0; r < 4; ++r)
                        mcap[(grp * 4 + r) * 132 + n0 + l16] = acc[r];
                }
            }
            __syncthreads();

            // --- P6: logits[k][l] += e_l . g_k ; (l,q) = (t>>2, t&3) ---
            {
                const int l = t >> 2, q = t & 3;
                const int wq = q * 32;
                float acc[8] = {0, 0, 0, 0, 0, 0, 0, 0};
#pragma unroll
                for (int jj = 0; jj < 8; ++jj) {
                    const float4 ev = *(const float4*)&eb[l * 128 + SWZ(l, wq + jj * 4)];
#pragma unroll
                    for (int k = 0; k < 8; ++k) {
                        const float4 gv = *(const float4*)&mcap[k * 132 + wq + jj * 4];
                        acc[k] += ev.x * gv.x + ev.y * gv.y + ev.z * gv.z + ev.w * gv.w;
                    }
                }
#pragma unroll
                for (int k = 0; k < 8; ++k) {
                    acc[k] += __shfl_xor(acc[k], 1);
                    acc[k] += __shfl_xor(acc[k], 2);
                }
                if (q == 0) {
#pragma unroll
                    for (int k = 0; k < 8; ++k) logits[k * 256 + l] += acc[k];
                }
            }
            __syncthreads();
        }
    }

    // --- mu_n = m / (||m|| + 1e-8)  (denom = sum_l softmax = 1 + 1e-8; cancels) ---
    if (wv < 8) {
        const int k = wv;
        const float x0 = mcap[k * 132 + lane];
        const float x1 = mcap[k * 132 + 64 + lane];
        float s = x0 * x0 + x1 * x1;
#pragma unroll
        for (int o = 32; o; o >>= 1) s += __shfl_xor(s, o);
        const float nv = sqrtf(s) + 1e-8f;
        mcap[k * 132 + lane] = x0 / nv;
        mcap[k * 132 + 64 + lane] = x1 / nv;
    }
    __syncthreads();

    // --- P9: svals[k] = sum_l c[k][l] * (e_l . mu_k) / enl[l] ---
    {
        const int l = t >> 2, q = t & 3;
        const int wq = q * 32;
        float acc[8] = {0, 0, 0, 0, 0, 0, 0, 0};
#pragma unroll
        for (int jj = 0; jj < 8; ++jj) {
            const float4 ev = *(const float4*)&eb[l * 128 + SWZ(l, wq + jj * 4)];
#pragma unroll
            for (int k = 0; k < 8; ++k) {
                const float4 mv = *(const float4*)&mcap[k * 132 + wq + jj * 4];
                acc[k] += ev.x * mv.x + ev.y * mv.y + ev.z * mv.z + ev.w * mv.w;
            }
        }
#pragma unroll
        for (int k = 0; k < 8; ++k) {
            acc[k] += __shfl_xor(acc[k], 1);
            acc[k] += __shfl_xor(acc[k], 2);
        }
        // After XOR 1,2 the quad is uniform. The XOR 4..32 butterfly below sums
        // ONE lane per quad (lanes == x mod 4), so each l contributes exactly
        // once -> weight is c/enl with NO duplicate-compensation factor.
        const float invel = 1.0f / enl[l];
        const float4 c0 = *(const float4*)&ct[CB(l)];
        const float4 c1 = *(const float4*)&ct[CB(l) + 4];
        acc[0] *= c0.x * invel; acc[1] *= c0.y * invel;
        acc[2] *= c0.z * invel; acc[3] *= c0.w * invel;
        acc[4] *= c1.x * invel; acc[5] *= c1.y * invel;
        acc[6] *= c1.z * invel; acc[7] *= c1.w * invel;
#pragma unroll
        for (int k = 0; k < 8; ++k) {
            acc[k] += __shfl_xor(acc[k], 4);
            acc[k] += __shfl_xor(acc[k], 8);
            acc[k] += __shfl_xor(acc[k], 16);
            acc[k] += __shfl_xor(acc[k], 32);
        }
        if (lane == 0) {
#pragma unroll
            for (int k = 0; k < 8; ++k) wavePart[wv * 8 + k] = acc[k];
        }
    }
    // --- P10: Gram pairs (2 per wave) ---
#pragma unroll
    for (int pp = 0; pp < 2; ++pp) {
        const int p = wv + pp * 16;
        if (p < 28) {
            int i = 0, rem = p;
            while (rem >= 7 - i) { rem -= 7 - i; ++i; }
            const int j = i + 1 + rem;
            float v = mcap[i * 132 + lane] * mcap[j * 132 + lane] +
                      mcap[i * 132 + 64 + lane] * mcap[j * 132 + 64 + lane];
#pragma unroll
            for (int o = 32; o; o >>= 1) v += __shfl_xor(v, o);
            if (lane == 0) Ps[p] = v;
        }
    }
    __syncthreads();
    if (t < 8) {
        float s = 0.f;
#pragma unroll
        for (int w = 0; w < 16; ++w) s += wavePart[w * 8 + t];
        svals[t] = s;
    }
    __syncthreads();

    // --- final serial scoring ---
    if (t == 0) {
        int idx[8];
        for (int i = 0; i < 8; ++i) idx[i] = i;
        for (int a = 1; a < 8; ++a) {
            const int key = idx[a];
            const float kv = strv[key];
            int bb = a - 1;
            while (bb >= 0 && strv[idx[bb]] < kv) { idx[bb + 1] = idx[bb]; --bb; }
            idx[bb + 1] = key;
        }
        float best = -1e30f;
        int bestk = 2;
        float cons_sum = 0.f, pair_sum = 0.f;
        for (int kk = 1; kk <= 8; ++kk) {
            const int ni = idx[kk - 1];
            cons_sum += svals[ni];
            for (int a = 0; a < kk - 1; ++a) {
                const int ia = idx[a];
                const int lo = ia < ni ? ia : ni;
                const int hi2 = ia < ni ? ni : ia;
                const int off0 = lo * 7 - lo * (lo - 1) / 2;
                pair_sum += Ps[off0 + hi2 - lo - 1];
            }
            if (kk >= 2) {
                const float cons = cons_sum / (kk * 256.0f);
                const float divv = 1.0f - (2.0f / (kk * (kk - 1))) * pair_sum;
                const float score = 0.5f * cons + 0.5f * divv;
                out[256 + b * 7 + (kk - 2)] = score;
                if (score > best) { best = score; bestk = kk; }
            }
        }
        out[b] = (float)bestk;
    }
}

// ---------------------------------------------------------------------------
extern "C" void kernel_launch(void* const* d_in, const int* in_sizes, int n_in,
                              void* d_out, int out_size, void* d_ws, size_t ws_size,
                              hipStream_t stream) {
    const float* e = (const float*)d_in[0];
    const float* W = (const float*)d_in[1];
    const float* b_init = (const float*)d_in[2];
    float* out = (float*)d_out;

    short* whi = (short*)d_ws;
    short* wlo = whi + 16384;
    short* wthi = wlo + 16384;
    short* wtlo = wthi + 16384;

    hipLaunchKernelGGL(setup_w_kernel, dim3(64), dim3(256), 0, stream, W, whi, wlo, wthi, wtlo);
    hipLaunchKernelGGL(fused_kernel, dim3(NB), dim3(1024), 0, stream,
                       e, b_init, whi, wlo, wthi, wtlo, out);
}

// Round 7
// 47.756 us; speedup vs baseline: 3.5501x; 1.3495x over previous
//
#include <hip/hip_runtime.h>
#include <hip/hip_bf16.h>
#include <math.h>

#define NB 256
#define NL 256
#define NH 128
#define NK 8

typedef __attribute__((ext_vector_type(8))) short bf16x8;
typedef __attribute__((ext_vector_type(4))) short s16x4;
typedef __attribute__((ext_vector_type(4))) float f32x4;

static __device__ __forceinline__ short f2bf(float x) {
    __hip_bfloat16 b = __float2bfloat16(x);
    return *reinterpret_cast<short*>(&b);
}
static __device__ __forceinline__ float bf2f(short s) {
    union { unsigned int u; float f; } v;
    v.u = ((unsigned int)(unsigned short)s) << 16;
    return v.f;
}

// c storage: [l][12] f32 with bank-spread offset; CTI(l,k) -> float index
#define CTI(l, k) ((l) * 12 + ((((l) >> 5) & 7) << 2) + (k))

// ---------------------------------------------------------------------------
// Setup: split W into bf16 hi/lo + transposed copies (global, L2-hot).
// ---------------------------------------------------------------------------
__global__ __launch_bounds__(256) void setup_w_kernel(const float* __restrict__ W,
                                                      short* __restrict__ whi,
                                                      short* __restrict__ wlo,
                                                      short* __restrict__ wthi,
                                                      short* __restrict__ wtlo) {
    const int id = blockIdx.x * 256 + threadIdx.x;   // h*128 + j
    const int h = id >> 7, j = id & 127;
    const float w = W[id];
    const short hi = f2bf(w);
    const short lo = f2bf(w - bf2f(hi));
    whi[id] = hi;
    wlo[id] = lo;
    wthi[j * 128 + h] = hi;
    wtlo[j * 128 + h] = lo;
}

// ---------------------------------------------------------------------------
// Fused per-batch kernel: 256 blocks x 1024 threads (16 waves).
// e LDS-resident as interleaved bf16 hi/lo: ebx[l*264 + g4*8 + {0..3:hi,4..7:lo}]
// logits in registers (lane l16 = capsule k, rows l = wv*16+grp*4+r).
// ---------------------------------------------------------------------------
__global__ __launch_bounds__(1024) void fused_kernel(const float* __restrict__ e,
                                                     const float* __restrict__ b_init,
                                                     const short* __restrict__ whi,
                                                     const short* __restrict__ wlo,
                                                     const short* __restrict__ wthi,
                                                     const short* __restrict__ wtlo,
                                                     float* __restrict__ out) {
    const int b = blockIdx.x;
    const int t = threadIdx.x;
    const int lane = t & 63, wv = t >> 6;
    const int l16 = lane & 15, grp = lane >> 4;

    __shared__ __align__(16) short ebx[NL * 264];      // 135168 B
    __shared__ __align__(16) float ct12[3096];         // 12384 B
    __shared__ __align__(16) short mhi[8 * 136];       // 2176 B each
    __shared__ __align__(16) short mlo2[8 * 136];
    __shared__ __align__(16) short caphi[8 * 136];
    __shared__ __align__(16) short caplo[8 * 136];
    __shared__ __align__(16) short ghi[8 * 136];       // g, then mu
    __shared__ __align__(16) short glo[8 * 136];
    __shared__ float enl[NL];                          // 1024 B
    __shared__ float red32[256];                       // 1024 B
    __shared__ float svals[8], strv[8], Ps[28];

    // ---- stage e -> bf16 hi/lo interleaved; row norms enl ----
    const float* ebg = e + (size_t)b * (NL * NH);
#pragma unroll
    for (int rep = 0; rep < 8; ++rep) {
        const int idx4 = rep * 1024 + t;
        const int l = idx4 >> 5, c4 = idx4 & 31;
        const float4 v = *(const float4*)&ebg[l * 128 + c4 * 4];
        const float vx[4] = {v.x, v.y, v.z, v.w};
        s16x4 hv, lv;
        float ss = 0.f;
#pragma unroll
        for (int j = 0; j < 4; ++j) {
            const short h = f2bf(vx[j]);
            hv[j] = h;
            lv[j] = f2bf(vx[j] - bf2f(h));
            ss += vx[j] * vx[j];
        }
        *(s16x4*)&ebx[l * 264 + c4 * 8] = hv;
        *(s16x4*)&ebx[l * 264 + c4 * 8 + 4] = lv;
        ss += __shfl_xor(ss, 1); ss += __shfl_xor(ss, 2);
        ss += __shfl_xor(ss, 4); ss += __shfl_xor(ss, 8);
        ss += __shfl_xor(ss, 16);
        if ((lane & 31) == 0) enl[l] = sqrtf(ss) + 1e-8f;
    }

    // ---- logits into registers ----
    float lr0 = 0.f, lr1 = 0.f, lr2 = 0.f, lr3 = 0.f;
    if (l16 < 8) {
        const float4 bi = *(const float4*)&b_init[(size_t)b * 2048 + l16 * 256 + wv * 16 + grp * 4];
        lr0 = bi.x; lr1 = bi.y; lr2 = bi.z; lr3 = bi.w;
    }
    __syncthreads();

    for (int iter = 0; iter < 3; ++iter) {
        // ===== P1: softmax over l (capsule k = l16) =====
        {
            float mx = fmaxf(fmaxf(lr0, lr1), fmaxf(lr2, lr3));
            mx = fmaxf(mx, __shfl_xor(mx, 16));
            mx = fmaxf(mx, __shfl_xor(mx, 32));
            if (l16 < 8 && grp == 0) red32[wv * 8 + l16] = mx;
            __syncthreads();
            float km = -1e30f;
#pragma unroll
            for (int w = 0; w < 16; ++w) km = fmaxf(km, red32[w * 8 + (l16 & 7)]);
            const float e0 = expf(lr0 - km), e1 = expf(lr1 - km);
            const float e2 = expf(lr2 - km), e3 = expf(lr3 - km);
            float s4 = e0 + e1 + e2 + e3;
            s4 += __shfl_xor(s4, 16); s4 += __shfl_xor(s4, 32);
            if (l16 < 8 && grp == 0) red32[128 + wv * 8 + l16] = s4;
            __syncthreads();
            float ksum = 0.f;
#pragma unroll
            for (int w = 0; w < 16; ++w) ksum += red32[128 + w * 8 + (l16 & 7)];
            const float inv = 1.0f / ksum;
            if (l16 < 8) {
                const int lb = wv * 16 + grp * 4;
                ct12[CTI(lb + 0, l16)] = e0 * inv;
                ct12[CTI(lb + 1, l16)] = e1 * inv;
                ct12[CTI(lb + 2, l16)] = e2 * inv;
                ct12[CTI(lb + 3, l16)] = e3 * inv;
            }
            __syncthreads();
        }

        // ===== P2: m[k][h] = sum_l c[k][l]*e[l][h]  (VALU, wide LDS reads) =====
        {
            const int lm = lane & 31, khalf = lane >> 5;
            const int h8 = wv;  // h-block: h = h8*8 + hh
            float acc[4][8];
#pragma unroll
            for (int kq = 0; kq < 4; ++kq)
#pragma unroll
                for (int hh = 0; hh < 8; ++hh) acc[kq][hh] = 0.f;
#pragma unroll
            for (int i = 0; i < 8; ++i) {
                const int l = i * 32 + lm;
                const float4 cv = *(const float4*)&ct12[l * 12 + (((l >> 5) & 7) << 2) + khalf * 4];
                const bf16x8 r1 = *(const bf16x8*)&ebx[l * 264 + h8 * 16];
                const bf16x8 r2 = *(const bf16x8*)&ebx[l * 264 + h8 * 16 + 8];
                float ev[8];
#pragma unroll
                for (int j = 0; j < 4; ++j) {
                    ev[j] = bf2f(r1[j]) + bf2f(r1[4 + j]);
                    ev[4 + j] = bf2f(r2[j]) + bf2f(r2[4 + j]);
                }
                const float cvx[4] = {cv.x, cv.y, cv.z, cv.w};
#pragma unroll
                for (int kq = 0; kq < 4; ++kq)
#pragma unroll
                    for (int hh = 0; hh < 8; ++hh)
                        acc[kq][hh] += cvx[kq] * ev[hh];
            }
            // scatter-reduce: 32 values over the 32 lanes of each khalf-half.
            // All register indices static; lane-bit selects via cndmask.
            float a1[16];
#pragma unroll
            for (int j = 0; j < 16; ++j) {
                const float keep = (lane & 1) ? acc[(2 * j + 1) >> 3][(2 * j + 1) & 7]
                                              : acc[(2 * j) >> 3][(2 * j) & 7];
                const float send = (lane & 1) ? acc[(2 * j) >> 3][(2 * j) & 7]
                                              : acc[(2 * j + 1) >> 3][(2 * j + 1) & 7];
                a1[j] = keep + __shfl_xor(send, 1);
            }
            float a2[8];
#pragma unroll
            for (int j = 0; j < 8; ++j) {
                const float keep = (lane & 2) ? a1[2 * j + 1] : a1[2 * j];
                const float send = (lane & 2) ? a1[2 * j] : a1[2 * j + 1];
                a2[j] = keep + __shfl_xor(send, 2);
            }
            float a3[4];
#pragma unroll
            for (int j = 0; j < 4; ++j) {
                const float keep = (lane & 4) ? a2[2 * j + 1] : a2[2 * j];
                const float send = (lane & 4) ? a2[2 * j] : a2[2 * j + 1];
                a3[j] = keep + __shfl_xor(send, 4);
            }
            float a4[2];
#pragma unroll
            for (int j = 0; j < 2; ++j) {
                const float keep = (lane & 8) ? a3[2 * j + 1] : a3[2 * j];
                const float send = (lane & 8) ? a3[2 * j] : a3[2 * j + 1];
                a4[j] = keep + __shfl_xor(send, 8);
            }
            const float keep5 = (lane & 16) ? a4[1] : a4[0];
            const float send5 = (lane & 16) ? a4[0] : a4[1];
            const float mval = keep5 + __shfl_xor(send5, 16);
            // lane holds m[k = khalf*4 + ((lane&31)>>3)][h = h8*8 + (lane&7)]
            const int mk = khalf * 4 + ((lane & 31) >> 3);
            const int mo = mk * 136 + h8 * 8 + (lane & 7);
            const short mhv = f2bf(mval);
            mhi[mo] = mhv;
            mlo2[mo] = f2bf(mval - bf2f(mhv));
        }
        __syncthreads();

        // ===== P3: cap = m @ W^T (split-bf16 MFMA, waves 0-7) =====
        if (wv < 8) {
            const int n0 = wv * 16;
            f32x4 acc = (f32x4){0.f, 0.f, 0.f, 0.f};
#pragma unroll
            for (int ks = 0; ks < 4; ++ks) {
                const int ao = (l16 & 7) * 136 + ks * 32 + grp * 8;
                const bf16x8 ah = *(const bf16x8*)&mhi[ao];
                const bf16x8 al = *(const bf16x8*)&mlo2[ao];
                const int bo = (n0 + l16) * 128 + ks * 32 + grp * 8;
                const bf16x8 bh = *(const bf16x8*)&whi[bo];
                const bf16x8 bl = *(const bf16x8*)&wlo[bo];
                acc = __builtin_amdgcn_mfma_f32_16x16x32_bf16(ah, bh, acc, 0, 0, 0);
                acc = __builtin_amdgcn_mfma_f32_16x16x32_bf16(al, bh, acc, 0, 0, 0);
                acc = __builtin_amdgcn_mfma_f32_16x16x32_bf16(ah, bl, acc, 0, 0, 0);
            }
            if (grp < 2) {
#pragma unroll
                for (int r = 0; r < 4; ++r) {
                    const float v = acc[r];
                    const short hv = f2bf(v);
                    const int o = (grp * 4 + r) * 136 + n0 + l16;
                    caphi[o] = hv;
                    caplo[o] = f2bf(v - bf2f(hv));
                }
            }
        }
        __syncthreads();

        // ===== P4: squash (+ strength on final iter) =====
        if (wv < 8) {
            const int k = wv;
            float x0 = bf2f(caphi[k * 136 + lane]) + bf2f(caplo[k * 136 + lane]);
            float x1 = bf2f(caphi[k * 136 + 64 + lane]) + bf2f(caplo[k * 136 + 64 + lane]);
            float s = x0 * x0 + x1 * x1;
#pragma unroll
            for (int o = 32; o; o >>= 1) s += __shfl_xor(s, o);
            const float sc = s / (1.0f + s) / sqrtf(s + 1e-9f);
            x0 *= sc; x1 *= sc;
            short hv = f2bf(x0);
            caphi[k * 136 + lane] = hv;
            caplo[k * 136 + lane] = f2bf(x0 - bf2f(hv));
            hv = f2bf(x1);
            caphi[k * 136 + 64 + lane] = hv;
            caplo[k * 136 + 64 + lane] = f2bf(x1 - bf2f(hv));
            if (iter == 2 && lane == 0)
                strv[k] = s / (1.0f + s) * sqrtf(s) / sqrtf(s + 1e-9f);
        }
        __syncthreads();

        if (iter < 2) {
            // ===== P5: g = cap @ W (split-bf16 MFMA, waves 0-7) =====
            if (wv < 8) {
                const int n0 = wv * 16;
                f32x4 acc = (f32x4){0.f, 0.f, 0.f, 0.f};
#pragma unroll
                for (int ks = 0; ks < 4; ++ks) {
                    const int ao = (l16 & 7) * 136 + ks * 32 + grp * 8;
                    const bf16x8 ah = *(const bf16x8*)&caphi[ao];
                    const bf16x8 al = *(const bf16x8*)&caplo[ao];
                    const int bo = (n0 + l16) * 128 + ks * 32 + grp * 8;
                    const bf16x8 bh = *(const bf16x8*)&wthi[bo];
                    const bf16x8 bl = *(const bf16x8*)&wtlo[bo];
                    acc = __builtin_amdgcn_mfma_f32_16x16x32_bf16(ah, bh, acc, 0, 0, 0);
                    acc = __builtin_amdgcn_mfma_f32_16x16x32_bf16(al, bh, acc, 0, 0, 0);
                    acc = __builtin_amdgcn_mfma_f32_16x16x32_bf16(ah, bl, acc, 0, 0, 0);
                }
                if (grp < 2) {
#pragma unroll
                    for (int r = 0; r < 4; ++r) {
                        const float v = acc[r];
                        const short hv = f2bf(v);
                        const int o = (grp * 4 + r) * 136 + n0 + l16;
                        ghi[o] = hv;
                        glo[o] = f2bf(v - bf2f(hv));
                    }
                }
            }
            __syncthreads();

            // ===== P6: logits += e . g  (MFMA, C-operand = logits, all waves) =====
            {
                const int m0 = wv * 16;
                f32x4 acc = (f32x4){lr0, lr1, lr2, lr3};
#pragma unroll
                for (int ks = 0; ks < 4; ++ks) {
                    const int eo = (m0 + l16) * 264 + ks * 64 + grp * 16;
                    const bf16x8 r1 = *(const bf16x8*)&ebx[eo];
                    const bf16x8 r2 = *(const bf16x8*)&ebx[eo + 8];
                    const bf16x8 ah = __builtin_shufflevector(r1, r2, 0, 1, 2, 3, 8, 9, 10, 11);
                    const bf16x8 al = __builtin_shufflevector(r1, r2, 4, 5, 6, 7, 12, 13, 14, 15);
                    const int bo = (l16 & 7) * 136 + ks * 32 + grp * 8;
                    const bf16x8 bh = *(const bf16x8*)&ghi[bo];
                    const bf16x8 bl = *(const bf16x8*)&glo[bo];
                    acc = __builtin_amdgcn_mfma_f32_16x16x32_bf16(ah, bh, acc, 0, 0, 0);
                    acc = __builtin_amdgcn_mfma_f32_16x16x32_bf16(al, bh, acc, 0, 0, 0);
                    acc = __builtin_amdgcn_mfma_f32_16x16x32_bf16(ah, bl, acc, 0, 0, 0);
                }
                lr0 = acc[0]; lr1 = acc[1]; lr2 = acc[2]; lr3 = acc[3];
            }
            // no barrier needed: next phase touching shared state is P1, whose
            // red32 write is ordered by its own __syncthreads.
        }
    }

    // ===== mu_n = m/||m||  -> bf16 into ghi/glo (waves 0-7) =====
    if (wv < 8) {
        const int k = wv;
        float x0 = bf2f(mhi[k * 136 + lane]) + bf2f(mlo2[k * 136 + lane]);
        float x1 = bf2f(mhi[k * 136 + 64 + lane]) + bf2f(mlo2[k * 136 + 64 + lane]);
        float s = x0 * x0 + x1 * x1;
#pragma unroll
        for (int o = 32; o; o >>= 1) s += __shfl_xor(s, o);
        const float nv = sqrtf(s) + 1e-8f;
        x0 /= nv; x1 /= nv;
        short hv = f2bf(x0);
        ghi[k * 136 + lane] = hv;
        glo[k * 136 + lane] = f2bf(x0 - bf2f(hv));
        hv = f2bf(x1);
        ghi[k * 136 + 64 + lane] = hv;
        glo[k * 136 + 64 + lane] = f2bf(x1 - bf2f(hv));
    }
    __syncthreads();

    // ===== P9: dot = e . mu (MFMA) + weight by c/enl =====
    {
        const int m0 = wv * 16;
        f32x4 acc = (f32x4){0.f, 0.f, 0.f, 0.f};
#pragma unroll
        for (int ks = 0; ks < 4; ++ks) {
            const int eo = (m0 + l16) * 264 + ks * 64 + grp * 16;
            const bf16x8 r1 = *(const bf16x8*)&ebx[eo];
            const bf16x8 r2 = *(const bf16x8*)&ebx[eo + 8];
            const bf16x8 ah = __builtin_shufflevector(r1, r2, 0, 1, 2, 3, 8, 9, 10, 11);
            const bf16x8 al = __builtin_shufflevector(r1, r2, 4, 5, 6, 7, 12, 13, 14, 15);
            const int bo = (l16 & 7) * 136 + ks * 32 + grp * 8;
            const bf16x8 bh = *(const bf16x8*)&ghi[bo];
            const bf16x8 bl = *(const bf16x8*)&glo[bo];
            acc = __builtin_amdgcn_mfma_f32_16x16x32_bf16(ah, bh, acc, 0, 0, 0);
            acc = __builtin_amdgcn_mfma_f32_16x16x32_bf16(al, bh, acc, 0, 0, 0);
            acc = __builtin_amdgcn_mfma_f32_16x16x32_bf16(ah, bl, acc, 0, 0, 0);
        }
        float sv = 0.f;
        if (l16 < 8) {
#pragma unroll
            for (int r = 0; r < 4; ++r) {
                const int l = m0 + grp * 4 + r;
                sv += acc[r] * ct12[CTI(l, l16)] / enl[l];
            }
        }
        sv += __shfl_xor(sv, 16);
        sv += __shfl_xor(sv, 32);
        if (l16 < 8 && grp == 0) red32[wv * 8 + l16] = sv;
    }

    // ===== Gram pairs from mu (2 per wave) =====
#pragma unroll
    for (int pp = 0; pp < 2; ++pp) {
        const int p = wv + pp * 16;
        if (p < 28) {
            int i = 0, rem = p;
            while (rem >= 7 - i) { rem -= 7 - i; ++i; }
            const int j = i + 1 + rem;
            const float mi0 = bf2f(ghi[i * 136 + lane]) + bf2f(glo[i * 136 + lane]);
            const float mi1 = bf2f(ghi[i * 136 + 64 + lane]) + bf2f(glo[i * 136 + 64 + lane]);
            const float mj0 = bf2f(ghi[j * 136 + lane]) + bf2f(glo[j * 136 + lane]);
            const float mj1 = bf2f(ghi[j * 136 + 64 + lane]) + bf2f(glo[j * 136 + 64 + lane]);
            float v = mi0 * mj0 + mi1 * mj1;
#pragma unroll
            for (int o = 32; o; o >>= 1) v += __shfl_xor(v, o);
            if (lane == 0) Ps[p] = v;
        }
    }
    __syncthreads();
    if (t < 8) {
        float s = 0.f;
#pragma unroll
        for (int w = 0; w < 16; ++w) s += red32[w * 8 + t];
        svals[t] = s;
    }
    __syncthreads();

    // ===== serial scoring =====
    if (t == 0) {
        int idx[8];
        for (int i = 0; i < 8; ++i) idx[i] = i;
        for (int a = 1; a < 8; ++a) {
            const int key = idx[a];
            const float kv = strv[key];
            int bb = a - 1;
            while (bb >= 0 && strv[idx[bb]] < kv) { idx[bb + 1] = idx[bb]; --bb; }
            idx[bb + 1] = key;
        }
        float best = -1e30f;
        int bestk = 2;
        float cons_sum = 0.f, pair_sum = 0.f;
        for (int kk = 1; kk <= 8; ++kk) {
            const int ni = idx[kk - 1];
            cons_sum += svals[ni];
            for (int a = 0; a < kk - 1; ++a) {
                const int ia = idx[a];
                const int lo = ia < ni ? ia : ni;
                const int hi2 = ia < ni ? ni : ia;
                const int off0 = lo * 7 - lo * (lo - 1) / 2;
                pair_sum += Ps[off0 + hi2 - lo - 1];
            }
            if (kk >= 2) {
                const float cons = cons_sum / (kk * 256.0f);
                const float divv = 1.0f - (2.0f / (kk * (kk - 1))) * pair_sum;
                const float score = 0.5f * cons + 0.5f * divv;
                out[256 + b * 7 + (kk - 2)] = score;
                if (score > best) { best = score; bestk = kk; }
            }
        }
        out[b] = (float)bestk;
    }
}

// ---------------------------------------------------------------------------
extern "C" void kernel_launch(void* const* d_in, const int* in_sizes, int n_in,
                              void* d_out, int out_size, void* d_ws, size_t ws_size,
                              hipStream_t stream) {
    const float* e = (const float*)d_in[0];
    const float* W = (const float*)d_in[1];
    const float* b_init = (const float*)d_in[2];
    float* out = (float*)d_out;

    short* whi = (short*)d_ws;
    short* wlo = whi + 16384;
    short* wthi = wlo + 16384;
    short* wtlo = wthi + 16384;

    hipLaunchKernelGGL(setup_w_kernel, dim3(64), dim3(256), 0, stream, W, whi, wlo, wthi, wtlo);
    hipLaunchKernelGGL(fused_kernel, dim3(NB), dim3(1024), 0, stream,
                       e, b_init, whi, wlo, wthi, wtlo, out);
}

// Round 9
// 46.432 us; speedup vs baseline: 3.6514x; 1.0285x over previous
//
#include <hip/hip_runtime.h>
#include <hip/hip_bf16.h>
#include <math.h>

#define NB 256
#define NL 256
#define NH 128
#define NK 8

typedef __attribute__((ext_vector_type(8))) short bf16x8;
typedef __attribute__((ext_vector_type(4))) short s16x4;
typedef __attribute__((ext_vector_type(4))) float f32x4;

static __device__ __forceinline__ short f2bf(float x) {
    __hip_bfloat16 b = __float2bfloat16(x);
    return *reinterpret_cast<short*>(&b);
}
static __device__ __forceinline__ float bf2f(short s) {
    union { unsigned int u; float f; } v;
    v.u = ((unsigned int)(unsigned short)s) << 16;
    return v.f;
}

// c storage: [l][12] f32 with bank-spread offset; CTI(l,k) -> float index
#define CTI(l, k) ((l) * 12 + ((((l) >> 5) & 7) << 2) + (k))
#define MFMA __builtin_amdgcn_mfma_f32_16x16x32_bf16

// ---------------------------------------------------------------------------
// Setup: split W into bf16 hi/lo + transposed copies (global, L2/L3-hot).
// ---------------------------------------------------------------------------
__global__ __launch_bounds__(256) void setup_w_kernel(const float* __restrict__ W,
                                                      short* __restrict__ whi,
                                                      short* __restrict__ wlo,
                                                      short* __restrict__ wthi,
                                                      short* __restrict__ wtlo) {
    const int id = blockIdx.x * 256 + threadIdx.x;   // h*128 + j
    const int h = id >> 7, j = id & 127;
    const float w = W[id];
    const short hi = f2bf(w);
    const short lo = f2bf(w - bf2f(hi));
    whi[id] = hi;
    wlo[id] = lo;
    wthi[j * 128 + h] = hi;
    wtlo[j * 128 + h] = lo;
}

// ---------------------------------------------------------------------------
// Fused per-batch kernel: 256 blocks x 1024 threads (16 waves).
// e LDS-resident interleaved bf16 hi/lo (round-7 verified layout);
// P3/P5 2-MFMA row-packed; P6/P9 2-MFMA col-packed with logits in C-operand;
// P2 = verified VALU scatter-butterfly.
// ---------------------------------------------------------------------------
__global__ __launch_bounds__(1024) void fused_kernel(const float* __restrict__ e,
                                                     const float* __restrict__ b_init,
                                                     const short* __restrict__ whi,
                                                     const short* __restrict__ wlo,
                                                     const short* __restrict__ wthi,
                                                     const short* __restrict__ wtlo,
                                                     float* __restrict__ out) {
    const int b = blockIdx.x;
    const int t = threadIdx.x;
    const int lane = t & 63, wv = t >> 6;
    const int l16 = lane & 15, grp = lane >> 4;

    __shared__ __align__(16) short ebx[NL * 264];   // 135168 B  e hi4|lo4 interleaved
    __shared__ __align__(16) float ct12[3096];      // 12384 B   c (f32, bank-spread)
    __shared__ __align__(16) short mpk[16 * 136];   // 4352 B    m: rows 0-7 hi, 8-15 lo
    __shared__ __align__(16) short cappk[16 * 136]; // 4352 B    squashed cap hi/lo
    __shared__ __align__(16) short gpk[16 * 136];   // 4352 B    g/mu hi/lo; ALIASED below
    __shared__ float enl[256];                      // 1024 B
    __shared__ float red32[128];                    // 512 B
    __shared__ float svals[8], strv[8], Ps[28];

    float* capb = (float*)gpk;  // f32 raw cap [8*136]; g dead during P3/P4 (lifetime ok)

    // ---- stage e -> interleaved bf16 hi/lo; row norms enl ----
    const float* ebg = e + (size_t)b * (NL * NH);
#pragma unroll
    for (int rep = 0; rep < 8; ++rep) {
        const int idx4 = rep * 1024 + t;
        const int l = idx4 >> 5, c4 = idx4 & 31;
        const float4 v = *(const float4*)&ebg[l * 128 + c4 * 4];
        const float vx[4] = {v.x, v.y, v.z, v.w};
        s16x4 hv, lv;
        float ss = 0.f;
#pragma unroll
        for (int j = 0; j < 4; ++j) {
            const short h = f2bf(vx[j]);
            hv[j] = h;
            lv[j] = f2bf(vx[j] - bf2f(h));
            ss += vx[j] * vx[j];
        }
        *(s16x4*)&ebx[l * 264 + c4 * 8] = hv;
        *(s16x4*)&ebx[l * 264 + c4 * 8 + 4] = lv;
        ss += __shfl_xor(ss, 1); ss += __shfl_xor(ss, 2);
        ss += __shfl_xor(ss, 4); ss += __shfl_xor(ss, 8);
        ss += __shfl_xor(ss, 16);
        if ((lane & 31) == 0) enl[l] = sqrtf(ss) + 1e-8f;
    }

    // ---- logits in registers: lane l16<8 = capsule k, l = wv*16+grp*4+r ----
    float lr0 = 0.f, lr1 = 0.f, lr2 = 0.f, lr3 = 0.f;
    if (l16 < 8) {
        const float4 bi = *(const float4*)&b_init[(size_t)b * 2048 + l16 * 256 + wv * 16 + grp * 4];
        lr0 = bi.x; lr1 = bi.y; lr2 = bi.z; lr3 = bi.w;
    }
    __syncthreads();

    for (int iter = 0; iter < 3; ++iter) {
        // ===== P1: softmax over l, no max-subtraction (|logits| <= ~61, f32-safe) =====
        {
            const float e0 = expf(lr0), e1 = expf(lr1);
            const float e2 = expf(lr2), e3 = expf(lr3);
            float s4 = e0 + e1 + e2 + e3;
            s4 += __shfl_xor(s4, 16);
            s4 += __shfl_xor(s4, 32);
            if (l16 < 8 && grp == 0) red32[wv * 8 + l16] = s4;
            __syncthreads();
            float ksum = 0.f;
#pragma unroll
            for (int w = 0; w < 16; ++w) ksum += red32[w * 8 + (l16 & 7)];
            const float inv = 1.0f / ksum;
            if (l16 < 8) {
                const int lb = wv * 16 + grp * 4;
                ct12[CTI(lb + 0, l16)] = e0 * inv;
                ct12[CTI(lb + 1, l16)] = e1 * inv;
                ct12[CTI(lb + 2, l16)] = e2 * inv;
                ct12[CTI(lb + 3, l16)] = e3 * inv;
            }
            __syncthreads();
        }

        // ===== P2: m[k][h] = sum_l c[k][l]*e[l][h]  (VALU scatter-butterfly) =====
        {
            const int lm = lane & 31, khalf = lane >> 5;
            const int h8 = wv;  // h-block: h = h8*8 + hh
            float acc[4][8];
#pragma unroll
            for (int kq = 0; kq < 4; ++kq)
#pragma unroll
                for (int hh = 0; hh < 8; ++hh) acc[kq][hh] = 0.f;
#pragma unroll
            for (int i = 0; i < 8; ++i) {
                const int l = i * 32 + lm;
                const float4 cv = *(const float4*)&ct12[l * 12 + (((l >> 5) & 7) << 2) + khalf * 4];
                const bf16x8 r1 = *(const bf16x8*)&ebx[l * 264 + h8 * 16];
                const bf16x8 r2 = *(const bf16x8*)&ebx[l * 264 + h8 * 16 + 8];
                float ev[8];
#pragma unroll
                for (int j = 0; j < 4; ++j) {
                    ev[j] = bf2f(r1[j]) + bf2f(r1[4 + j]);
                    ev[4 + j] = bf2f(r2[j]) + bf2f(r2[4 + j]);
                }
                const float cvx[4] = {cv.x, cv.y, cv.z, cv.w};
#pragma unroll
                for (int kq = 0; kq < 4; ++kq)
#pragma unroll
                    for (int hh = 0; hh < 8; ++hh)
                        acc[kq][hh] += cvx[kq] * ev[hh];
            }
            // scatter-reduce butterfly (verified round 7): static indices only
            float a1[16];
#pragma unroll
            for (int j = 0; j < 16; ++j) {
                const float keep = (lane & 1) ? acc[(2 * j + 1) >> 3][(2 * j + 1) & 7]
                                              : acc[(2 * j) >> 3][(2 * j) & 7];
                const float send = (lane & 1) ? acc[(2 * j) >> 3][(2 * j) & 7]
                                              : acc[(2 * j + 1) >> 3][(2 * j + 1) & 7];
                a1[j] = keep + __shfl_xor(send, 1);
            }
            float a2[8];
#pragma unroll
            for (int j = 0; j < 8; ++j) {
                const float keep = (lane & 2) ? a1[2 * j + 1] : a1[2 * j];
                const float send = (lane & 2) ? a1[2 * j] : a1[2 * j + 1];
                a2[j] = keep + __shfl_xor(send, 2);
            }
            float a3[4];
#pragma unroll
            for (int j = 0; j < 4; ++j) {
                const float keep = (lane & 4) ? a2[2 * j + 1] : a2[2 * j];
                const float send = (lane & 4) ? a2[2 * j] : a2[2 * j + 1];
                a3[j] = keep + __shfl_xor(send, 4);
            }
            float a4[2];
#pragma unroll
            for (int j = 0; j < 2; ++j) {
                const float keep = (lane & 8) ? a3[2 * j + 1] : a3[2 * j];
                const float send = (lane & 8) ? a3[2 * j] : a3[2 * j + 1];
                a4[j] = keep + __shfl_xor(send, 8);
            }
            const float keep5 = (lane & 16) ? a4[1] : a4[0];
            const float send5 = (lane & 16) ? a4[0] : a4[1];
            const float mval = keep5 + __shfl_xor(send5, 16);
            // lane holds m[k = khalf*4 + ((lane&31)>>3)][h = h8*8 + (lane&7)]
            const int mk = khalf * 4 + ((lane & 31) >> 3);
            const int mo = mk * 136 + h8 * 8 + (lane & 7);
            const short mhv = f2bf(mval);
            mpk[mo] = mhv;
            mpk[(mk + 8) * 136 + mo - mk * 136] = f2bf(mval - bf2f(mhv));
        }
        __syncthreads();

        // ===== P3: cap = m @ W^T  (A=[m_hi;m_lo] rows, 2 MFMAs/k-step) =====
        if (wv < 8) {
            const int n0 = wv * 16;
            f32x4 acc = (f32x4){0.f, 0.f, 0.f, 0.f};
#pragma unroll
            for (int ks = 0; ks < 4; ++ks) {
                const bf16x8 af = *(const bf16x8*)&mpk[l16 * 136 + ks * 32 + grp * 8];
                const int bo = (n0 + l16) * 128 + ks * 32 + grp * 8;
                acc = MFMA(af, *(const bf16x8*)&whi[bo], acc, 0, 0, 0);
                acc = MFMA(af, *(const bf16x8*)&wlo[bo], acc, 0, 0, 0);
            }
            f32x4 cs;
#pragma unroll
            for (int r = 0; r < 4; ++r) cs[r] = acc[r] + __shfl_xor(acc[r], 32);
            if (grp < 2) {
#pragma unroll
                for (int r = 0; r < 4; ++r)
                    capb[(grp * 4 + r) * 136 + n0 + l16] = cs[r];
            }
        }
        __syncthreads();

        // ===== P4: squash (wave-local over h), write cap hi/lo =====
        if (wv < 8) {
            const int k = wv;
            float x0 = capb[k * 136 + lane], x1 = capb[k * 136 + 64 + lane];
            float s = x0 * x0 + x1 * x1;
#pragma unroll
            for (int o = 32; o; o >>= 1) s += __shfl_xor(s, o);
            const float sc = s / (1.0f + s) / sqrtf(s + 1e-9f);
            x0 *= sc; x1 *= sc;
            short hv = f2bf(x0);
            cappk[k * 136 + lane] = hv;
            cappk[(k + 8) * 136 + lane] = f2bf(x0 - bf2f(hv));
            hv = f2bf(x1);
            cappk[k * 136 + 64 + lane] = hv;
            cappk[(k + 8) * 136 + 64 + lane] = f2bf(x1 - bf2f(hv));
            if (iter == 2 && lane == 0)
                strv[k] = s / (1.0f + s) * sqrtf(s) / sqrtf(s + 1e-9f);
        }
        __syncthreads();

        if (iter < 2) {
            // ===== P5: g = cap @ W  (A=[cap_hi;cap_lo], B=W^T global) =====
            if (wv < 8) {
                const int n0 = wv * 16;
                f32x4 acc = (f32x4){0.f, 0.f, 0.f, 0.f};
#pragma unroll
                for (int ks = 0; ks < 4; ++ks) {
                    const bf16x8 af = *(const bf16x8*)&cappk[l16 * 136 + ks * 32 + grp * 8];
                    const int bo = (n0 + l16) * 128 + ks * 32 + grp * 8;
                    acc = MFMA(af, *(const bf16x8*)&wthi[bo], acc, 0, 0, 0);
                    acc = MFMA(af, *(const bf16x8*)&wtlo[bo], acc, 0, 0, 0);
                }
                f32x4 gs;
#pragma unroll
                for (int r = 0; r < 4; ++r) gs[r] = acc[r] + __shfl_xor(acc[r], 32);
                if (grp < 2) {
#pragma unroll
                    for (int r = 0; r < 4; ++r) {
                        const int k = grp * 4 + r, h = n0 + l16;
                        const short hv = f2bf(gs[r]);
                        gpk[k * 136 + h] = hv;
                        gpk[(k + 8) * 136 + h] = f2bf(gs[r] - bf2f(hv));
                    }
                }
            }
            __syncthreads();

            // ===== P6: logits += e . g  (A=e hi/lo, B=[g_hi|g_lo] cols, C=logits) =====
            {
                const int m0 = wv * 16;
                f32x4 acc;
                acc[0] = (l16 < 8) ? lr0 : 0.f;
                acc[1] = (l16 < 8) ? lr1 : 0.f;
                acc[2] = (l16 < 8) ? lr2 : 0.f;
                acc[3] = (l16 < 8) ? lr3 : 0.f;
#pragma unroll
                for (int ks = 0; ks < 4; ++ks) {
                    const int eo = (m0 + l16) * 264 + ks * 64 + grp * 16;
                    const bf16x8 r1 = *(const bf16x8*)&ebx[eo];
                    const bf16x8 r2 = *(const bf16x8*)&ebx[eo + 8];
                    const bf16x8 ah = __builtin_shufflevector(r1, r2, 0, 1, 2, 3, 8, 9, 10, 11);
                    const bf16x8 al = __builtin_shufflevector(r1, r2, 4, 5, 6, 7, 12, 13, 14, 15);
                    const bf16x8 bf = *(const bf16x8*)&gpk[l16 * 136 + ks * 32 + grp * 8];
                    acc = MFMA(ah, bf, acc, 0, 0, 0);
                    acc = MFMA(al, bf, acc, 0, 0, 0);
                }
                // combine cols k and k+8 (lane^8)
                lr0 = acc[0] + __shfl_xor(acc[0], 8);
                lr1 = acc[1] + __shfl_xor(acc[1], 8);
                lr2 = acc[2] + __shfl_xor(acc[2], 8);
                lr3 = acc[3] + __shfl_xor(acc[3], 8);
            }
            // no barrier: next shared access (P1 red32) is separated by P1's sync
        }
    }

    // ===== mu_n = m / (||m|| + 1e-8) -> gpk hi/lo (g dead; capb dead) =====
    if (wv < 8) {
        const int k = wv;
        float x0 = bf2f(mpk[k * 136 + lane]) + bf2f(mpk[(k + 8) * 136 + lane]);
        float x1 = bf2f(mpk[k * 136 + 64 + lane]) + bf2f(mpk[(k + 8) * 136 + 64 + lane]);
        float s = x0 * x0 + x1 * x1;
#pragma unroll
        for (int o = 32; o; o >>= 1) s += __shfl_xor(s, o);
        const float nv = sqrtf(s) + 1e-8f;
        x0 /= nv; x1 /= nv;
        short hv = f2bf(x0);
        gpk[k * 136 + lane] = hv;
        gpk[(k + 8) * 136 + lane] = f2bf(x0 - bf2f(hv));
        hv = f2bf(x1);
        gpk[k * 136 + 64 + lane] = hv;
        gpk[(k + 8) * 136 + 64 + lane] = f2bf(x1 - bf2f(hv));
    }
    __syncthreads();

    // ===== P9: dot = e . mu (MFMA col-packed), weight by c/enl, reduce =====
    {
        const int m0 = wv * 16;
        f32x4 acc = (f32x4){0.f, 0.f, 0.f, 0.f};
#pragma unroll
        for (int ks = 0; ks < 4; ++ks) {
            const int eo = (m0 + l16) * 264 + ks * 64 + grp * 16;
            const bf16x8 r1 = *(const bf16x8*)&ebx[eo];
            const bf16x8 r2 = *(const bf16x8*)&ebx[eo + 8];
            const bf16x8 ah = __builtin_shufflevector(r1, r2, 0, 1, 2, 3, 8, 9, 10, 11);
            const bf16x8 al = __builtin_shufflevector(r1, r2, 4, 5, 6, 7, 12, 13, 14, 15);
            const bf16x8 bf = *(const bf16x8*)&gpk[l16 * 136 + ks * 32 + grp * 8];
            acc = MFMA(ah, bf, acc, 0, 0, 0);
            acc = MFMA(al, bf, acc, 0, 0, 0);
        }
        f32x4 d;
#pragma unroll
        for (int r = 0; r < 4; ++r) d[r] = acc[r] + __shfl_xor(acc[r], 8);
        float sv = 0.f;
        if (l16 < 8) {
#pragma unroll
            for (int r = 0; r < 4; ++r) {
                const int l = m0 + grp * 4 + r;
                sv += d[r] * ct12[CTI(l, l16)] / enl[l];
            }
        }
        sv += __shfl_xor(sv, 16);
        sv += __shfl_xor(sv, 32);
        if (l16 < 8 && grp == 0) red32[wv * 8 + l16] = sv;
    }

    // ===== Gram pairs from mu (2 per wave) =====
#pragma unroll
    for (int pp = 0; pp < 2; ++pp) {
        const int p = wv + pp * 16;
        if (p < 28) {
            int i = 0, rem = p;
            while (rem >= 7 - i) { rem -= 7 - i; ++i; }
            const int j = i + 1 + rem;
            const float mi0 = bf2f(gpk[i * 136 + lane]) + bf2f(gpk[(i + 8) * 136 + lane]);
            const float mi1 = bf2f(gpk[i * 136 + 64 + lane]) + bf2f(gpk[(i + 8) * 136 + 64 + lane]);
            const float mj0 = bf2f(gpk[j * 136 + lane]) + bf2f(gpk[(j + 8) * 136 + lane]);
            const float mj1 = bf2f(gpk[j * 136 + 64 + lane]) + bf2f(gpk[(j + 8) * 136 + 64 + lane]);
            float v = mi0 * mj0 + mi1 * mj1;
#pragma unroll
            for (int o = 32; o; o >>= 1) v += __shfl_xor(v, o);
            if (lane == 0) Ps[p] = v;
        }
    }
    __syncthreads();
    if (t < 8) {
        float s = 0.f;
#pragma unroll
        for (int w = 0; w < 16; ++w) s += red32[w * 8 + t];
        svals[t] = s;
    }
    __syncthreads();

    // ===== serial scoring =====
    if (t == 0) {
        int idx[8];
        for (int i = 0; i < 8; ++i) idx[i] = i;
        for (int a = 1; a < 8; ++a) {
            const int key = idx[a];
            const float kv = strv[key];
            int bb = a - 1;
            while (bb >= 0 && strv[idx[bb]] < kv) { idx[bb + 1] = idx[bb]; --bb; }
            idx[bb + 1] = key;
        }
        float best = -1e30f;
        int bestk = 2;
        float cons_sum = 0.f, pair_sum = 0.f;
        for (int kk = 1; kk <= 8; ++kk) {
            const int ni = idx[kk - 1];
            cons_sum += svals[ni];
            for (int a = 0; a < kk - 1; ++a) {
                const int ia = idx[a];
                const int lo = ia < ni ? ia : ni;
                const int hi2 = ia < ni ? ni : ia;
                const int off0 = lo * 7 - lo * (lo - 1) / 2;
                pair_sum += Ps[off0 + hi2 - lo - 1];
            }
            if (kk >= 2) {
                const float cons = cons_sum / (kk * 256.0f);
                const float divv = 1.0f - (2.0f / (kk * (kk - 1))) * pair_sum;
                const float score = 0.5f * cons + 0.5f * divv;
                out[256 + b * 7 + (kk - 2)] = score;
                if (score > best) { best = score; bestk = kk; }
            }
        }
        out[b] = (float)bestk;
    }
}

// ---------------------------------------------------------------------------
extern "C" void kernel_launch(void* const* d_in, const int* in_sizes, int n_in,
                              void* d_out, int out_size, void* d_ws, size_t ws_size,
                              hipStream_t stream) {
    const float* e = (const float*)d_in[0];
    const float* W = (const float*)d_in[1];
    const float* b_init = (const float*)d_in[2];
    float* out = (float*)d_out;

    short* whi = (short*)d_ws;
    short* wlo = whi + 16384;
    short* wthi = wlo + 16384;
    short* wtlo = wthi + 16384;

    hipLaunchKernelGGL(setup_w_kernel, dim3(64), dim3(256), 0, stream, W, whi, wlo, wthi, wtlo);
    hipLaunchKernelGGL(fused_kernel, dim3(NB), dim3(1024), 0, stream,
                       e, b_init, whi, wlo, wthi, wtlo, out);
}

// Round 10
// 39.538 us; speedup vs baseline: 4.2880x; 1.1744x over previous
//
#include <hip/hip_runtime.h>
#include <hip/hip_bf16.h>
#include <math.h>

#define NB 256
#define NL 256
#define NH 128
#define NK 8

typedef __attribute__((ext_vector_type(8))) short bf16x8;
typedef __attribute__((ext_vector_type(4))) short s16x4;
typedef __attribute__((ext_vector_type(4))) float f32x4;

static __device__ __forceinline__ short f2bf(float x) {
    __hip_bfloat16 b = __float2bfloat16(x);
    return *reinterpret_cast<short*>(&b);
}
static __device__ __forceinline__ float bf2f(short s) {
    union { unsigned int u; float f; } v;
    v.u = ((unsigned int)(unsigned short)s) << 16;
    return v.f;
}

#define MFMA __builtin_amdgcn_mfma_f32_16x16x32_bf16

// ---------------------------------------------------------------------------
// Setup: split W into bf16 hi/lo + transposed copies (global, L2/L3-hot).
// ---------------------------------------------------------------------------
__global__ __launch_bounds__(256) void setup_w_kernel(const float* __restrict__ W,
                                                      short* __restrict__ whi,
                                                      short* __restrict__ wlo,
                                                      short* __restrict__ wthi,
                                                      short* __restrict__ wtlo) {
    const int id = blockIdx.x * 256 + threadIdx.x;   // h*128 + j
    const int h = id >> 7, j = id & 127;
    const float w = W[id];
    const short hi = f2bf(w);
    const short lo = f2bf(w - bf2f(hi));
    whi[id] = hi;
    wlo[id] = lo;
    wthi[j * 128 + h] = hi;
    wtlo[j * 128 + h] = lo;
}

// ---------------------------------------------------------------------------
// Fused per-batch kernel: 256 blocks x 1024 threads (16 waves).
// ALL O(L*H) phases are MFMA. eT[h][l] bf16 hi/lo in LDS serves P2's B-operand;
// P6/P9's e A-fragments live in 32 VGPRs/lane (preloaded from global).
// ---------------------------------------------------------------------------
__global__ __launch_bounds__(1024) void fused_kernel(const float* __restrict__ e,
                                                     const float* __restrict__ b_init,
                                                     const short* __restrict__ whi,
                                                     const short* __restrict__ wlo,
                                                     const short* __restrict__ wthi,
                                                     const short* __restrict__ wtlo,
                                                     float* __restrict__ out) {
    const int b = blockIdx.x;
    const int t = threadIdx.x;
    const int lane = t & 63, wv = t >> 6;
    const int l16 = lane & 15, grp = lane >> 4;

    __shared__ __align__(16) short eThi[128 * 264]; // 67584 B  e^T hi
    __shared__ __align__(16) short eTlo[128 * 264]; // 67584 B  e^T lo
    __shared__ __align__(16) short cax[16 * 264];   // 8448 B   c rows 0-7 hi, 8-15 lo
    __shared__ __align__(16) short mpk[16 * 136];   // 4352 B   m hi/lo
    __shared__ __align__(16) short cappk[16 * 136]; // 4352 B   squashed cap hi/lo
    __shared__ __align__(16) short gpk[16 * 136];   // 4352 B   g/mu hi/lo (aliased f32 below)
    __shared__ float enl[256];                      // 1024 B
    __shared__ float red32[128];                    // 512 B
    __shared__ float svals[8], strv[8], Ps[28];     // 176 B    (total 158384 B)

    float* capb = (float*)gpk;  // raw f32 cap; g dead during P3/P4 (lifetime ok)

    const float* ebg = e + (size_t)b * (NL * NH);

    // ---- preload per-lane e row-fragments (P6/P9 A-operand) + row norms ----
    // lane (wv,l16,grp) owns row wv*16+l16, cols {ks*32+grp*8 .. +8}, ks=0..3
    bf16x8 eah[4], eal[4];
    {
        const int row = wv * 16 + l16;
        float ss = 0.f;
#pragma unroll
        for (int ks = 0; ks < 4; ++ks) {
            const float4 f0 = *(const float4*)&ebg[row * 128 + ks * 32 + grp * 8];
            const float4 f1 = *(const float4*)&ebg[row * 128 + ks * 32 + grp * 8 + 4];
            const float fx[8] = {f0.x, f0.y, f0.z, f0.w, f1.x, f1.y, f1.z, f1.w};
            bf16x8 hv, lv;
#pragma unroll
            for (int j = 0; j < 8; ++j) {
                const short h = f2bf(fx[j]);
                hv[j] = h;
                lv[j] = f2bf(fx[j] - bf2f(h));
                ss += fx[j] * fx[j];
            }
            eah[ks] = hv;
            eal[ks] = lv;
        }
        // grp lanes 0-3 of a row partition its 128 cols: xor16+xor32 = full norm
        ss += __shfl_xor(ss, 16);
        ss += __shfl_xor(ss, 32);
        if (grp == 0) enl[wv * 16 + l16] = sqrtf(ss) + 1e-8f;
    }

    // ---- stage e^T (bf16 hi/lo): coalesced column-gather from global ----
#pragma unroll
    for (int i = 0; i < 4; ++i) {
        const int p = i * 1024 + t;
        const int h = p & 127, c = p >> 7;   // c = l-chunk of 8
        float le[8];
#pragma unroll
        for (int j = 0; j < 8; ++j) le[j] = ebg[(c * 8 + j) * 128 + h];
        bf16x8 hv, lv;
#pragma unroll
        for (int j = 0; j < 8; ++j) {
            const short s = f2bf(le[j]);
            hv[j] = s;
            lv[j] = f2bf(le[j] - bf2f(s));
        }
        *(bf16x8*)&eThi[h * 264 + c * 8] = hv;
        *(bf16x8*)&eTlo[h * 264 + c * 8] = lv;
    }

    // ---- logits in registers: lane l16<8 = capsule k, l = wv*16+grp*4+r ----
    float lr0 = 0.f, lr1 = 0.f, lr2 = 0.f, lr3 = 0.f;
    if (l16 < 8) {
        const float4 bi = *(const float4*)&b_init[(size_t)b * 2048 + l16 * 256 + wv * 16 + grp * 4];
        lr0 = bi.x; lr1 = bi.y; lr2 = bi.z; lr3 = bi.w;
    }
    __syncthreads();

    for (int iter = 0; iter < 3; ++iter) {
        // ===== P1: softmax over l (no max-subtraction; |logits| <= ~61, f32-safe);
        //           write c as bf16 hi/lo in A-fragment layout =====
        {
            const float e0 = expf(lr0), e1 = expf(lr1);
            const float e2 = expf(lr2), e3 = expf(lr3);
            float s4 = e0 + e1 + e2 + e3;
            s4 += __shfl_xor(s4, 16);
            s4 += __shfl_xor(s4, 32);
            if (l16 < 8 && grp == 0) red32[wv * 8 + l16] = s4;
            __syncthreads();
            float ksum = 0.f;
#pragma unroll
            for (int w = 0; w < 16; ++w) ksum += red32[w * 8 + (l16 & 7)];
            const float inv = 1.0f / ksum;
            if (l16 < 8) {
                const int lb = wv * 16 + grp * 4;
                const float cv[4] = {e0 * inv, e1 * inv, e2 * inv, e3 * inv};
                s16x4 his, los;
#pragma unroll
                for (int j = 0; j < 4; ++j) {
                    const short h = f2bf(cv[j]);
                    his[j] = h;
                    los[j] = f2bf(cv[j] - bf2f(h));
                }
                *(s16x4*)&cax[l16 * 264 + lb] = his;
                *(s16x4*)&cax[(l16 + 8) * 264 + lb] = los;
            }
            __syncthreads();
        }

        // ===== P2: m = c @ e  (MFMA: A=[c_hi;c_lo] rows, B=eT hi/lo, waves 0-7) =====
        if (wv < 8) {
            const int n0 = wv * 16;  // h-block
            f32x4 acc = (f32x4){0.f, 0.f, 0.f, 0.f};
#pragma unroll
            for (int ks = 0; ks < 8; ++ks) {
                const bf16x8 af = *(const bf16x8*)&cax[l16 * 264 + ks * 32 + grp * 8];
                const bf16x8 bh = *(const bf16x8*)&eThi[(n0 + l16) * 264 + ks * 32 + grp * 8];
                const bf16x8 bl = *(const bf16x8*)&eTlo[(n0 + l16) * 264 + ks * 32 + grp * 8];
                acc = MFMA(af, bh, acc, 0, 0, 0);
                acc = MFMA(af, bl, acc, 0, 0, 0);
            }
            f32x4 ms;
#pragma unroll
            for (int r = 0; r < 4; ++r) ms[r] = acc[r] + __shfl_xor(acc[r], 32);
            if (grp < 2) {
#pragma unroll
                for (int r = 0; r < 4; ++r) {
                    const int k = grp * 4 + r, h = n0 + l16;
                    const short hv = f2bf(ms[r]);
                    mpk[k * 136 + h] = hv;
                    mpk[(k + 8) * 136 + h] = f2bf(ms[r] - bf2f(hv));
                }
            }
        }
        __syncthreads();

        // ===== P3: cap = m @ W^T  (A=[m_hi;m_lo] rows, B=W global) =====
        if (wv < 8) {
            const int n0 = wv * 16;
            f32x4 acc = (f32x4){0.f, 0.f, 0.f, 0.f};
#pragma unroll
            for (int ks = 0; ks < 4; ++ks) {
                const bf16x8 af = *(const bf16x8*)&mpk[l16 * 136 + ks * 32 + grp * 8];
                const int bo = (n0 + l16) * 128 + ks * 32 + grp * 8;
                acc = MFMA(af, *(const bf16x8*)&whi[bo], acc, 0, 0, 0);
                acc = MFMA(af, *(const bf16x8*)&wlo[bo], acc, 0, 0, 0);
            }
            f32x4 cs;
#pragma unroll
            for (int r = 0; r < 4; ++r) cs[r] = acc[r] + __shfl_xor(acc[r], 32);
            if (grp < 2) {
#pragma unroll
                for (int r = 0; r < 4; ++r)
                    capb[(grp * 4 + r) * 136 + n0 + l16] = cs[r];
            }
        }
        __syncthreads();

        // ===== P4: squash (wave-local over h), write cap hi/lo =====
        if (wv < 8) {
            const int k = wv;
            float x0 = capb[k * 136 + lane], x1 = capb[k * 136 + 64 + lane];
            float s = x0 * x0 + x1 * x1;
#pragma unroll
            for (int o = 32; o; o >>= 1) s += __shfl_xor(s, o);
            const float sc = s / (1.0f + s) / sqrtf(s + 1e-9f);
            x0 *= sc; x1 *= sc;
            short hv = f2bf(x0);
            cappk[k * 136 + lane] = hv;
            cappk[(k + 8) * 136 + lane] = f2bf(x0 - bf2f(hv));
            hv = f2bf(x1);
            cappk[k * 136 + 64 + lane] = hv;
            cappk[(k + 8) * 136 + 64 + lane] = f2bf(x1 - bf2f(hv));
            if (iter == 2 && lane == 0)
                strv[k] = s / (1.0f + s) * sqrtf(s) / sqrtf(s + 1e-9f);
        }
        __syncthreads();

        if (iter < 2) {
            // ===== P5: g = cap @ W  (A=[cap_hi;cap_lo], B=W^T global) =====
            if (wv < 8) {
                const int n0 = wv * 16;
                f32x4 acc = (f32x4){0.f, 0.f, 0.f, 0.f};
#pragma unroll
                for (int ks = 0; ks < 4; ++ks) {
                    const bf16x8 af = *(const bf16x8*)&cappk[l16 * 136 + ks * 32 + grp * 8];
                    const int bo = (n0 + l16) * 128 + ks * 32 + grp * 8;
                    acc = MFMA(af, *(const bf16x8*)&wthi[bo], acc, 0, 0, 0);
                    acc = MFMA(af, *(const bf16x8*)&wtlo[bo], acc, 0, 0, 0);
                }
                f32x4 gs;
#pragma unroll
                for (int r = 0; r < 4; ++r) gs[r] = acc[r] + __shfl_xor(acc[r], 32);
                if (grp < 2) {
#pragma unroll
                    for (int r = 0; r < 4; ++r) {
                        const int k = grp * 4 + r, h = n0 + l16;
                        const short hv = f2bf(gs[r]);
                        gpk[k * 136 + h] = hv;
                        gpk[(k + 8) * 136 + h] = f2bf(gs[r] - bf2f(hv));
                    }
                }
            }
            __syncthreads();

            // ===== P6: logits += e . g  (A = e regs, B=[g_hi|g_lo] cols, C=logits) =====
            {
                f32x4 acc;
                acc[0] = (l16 < 8) ? lr0 : 0.f;
                acc[1] = (l16 < 8) ? lr1 : 0.f;
                acc[2] = (l16 < 8) ? lr2 : 0.f;
                acc[3] = (l16 < 8) ? lr3 : 0.f;
#pragma unroll
                for (int ks = 0; ks < 4; ++ks) {
                    const bf16x8 bf = *(const bf16x8*)&gpk[l16 * 136 + ks * 32 + grp * 8];
                    acc = MFMA(eah[ks], bf, acc, 0, 0, 0);
                    acc = MFMA(eal[ks], bf, acc, 0, 0, 0);
                }
                lr0 = acc[0] + __shfl_xor(acc[0], 8);
                lr1 = acc[1] + __shfl_xor(acc[1], 8);
                lr2 = acc[2] + __shfl_xor(acc[2], 8);
                lr3 = acc[3] + __shfl_xor(acc[3], 8);
            }
            // no barrier: next shared access (P1 red32) is behind P1's own sync
        }
    }

    // ===== mu_n = m / (||m|| + 1e-8) -> gpk hi/lo =====
    if (wv < 8) {
        const int k = wv;
        float x0 = bf2f(mpk[k * 136 + lane]) + bf2f(mpk[(k + 8) * 136 + lane]);
        float x1 = bf2f(mpk[k * 136 + 64 + lane]) + bf2f(mpk[(k + 8) * 136 + 64 + lane]);
        float s = x0 * x0 + x1 * x1;
#pragma unroll
        for (int o = 32; o; o >>= 1) s += __shfl_xor(s, o);
        const float nv = sqrtf(s) + 1e-8f;
        x0 /= nv; x1 /= nv;
        short hv = f2bf(x0);
        gpk[k * 136 + lane] = hv;
        gpk[(k + 8) * 136 + lane] = f2bf(x0 - bf2f(hv));
        hv = f2bf(x1);
        gpk[k * 136 + 64 + lane] = hv;
        gpk[(k + 8) * 136 + 64 + lane] = f2bf(x1 - bf2f(hv));
    }
    __syncthreads();

    // ===== P9: dot = e . mu (A = e regs), weight by c/enl, reduce =====
    {
        f32x4 acc = (f32x4){0.f, 0.f, 0.f, 0.f};
#pragma unroll
        for (int ks = 0; ks < 4; ++ks) {
            const bf16x8 bf = *(const bf16x8*)&gpk[l16 * 136 + ks * 32 + grp * 8];
            acc = MFMA(eah[ks], bf, acc, 0, 0, 0);
            acc = MFMA(eal[ks], bf, acc, 0, 0, 0);
        }
        f32x4 d;
#pragma unroll
        for (int r = 0; r < 4; ++r) d[r] = acc[r] + __shfl_xor(acc[r], 8);
        float sv = 0.f;
        if (l16 < 8) {
#pragma unroll
            for (int r = 0; r < 4; ++r) {
                const int l = wv * 16 + grp * 4 + r;
                const float cv = bf2f(cax[l16 * 264 + l]) + bf2f(cax[(l16 + 8) * 264 + l]);
                sv += d[r] * cv / enl[l];
            }
        }
        sv += __shfl_xor(sv, 16);
        sv += __shfl_xor(sv, 32);
        if (l16 < 8 && grp == 0) red32[wv * 8 + l16] = sv;
    }

    // ===== Gram pairs from mu (2 per wave) =====
#pragma unroll
    for (int pp = 0; pp < 2; ++pp) {
        const int p = wv + pp * 16;
        if (p < 28) {
            int i = 0, rem = p;
            while (rem >= 7 - i) { rem -= 7 - i; ++i; }
            const int j = i + 1 + rem;
            const float mi0 = bf2f(gpk[i * 136 + lane]) + bf2f(gpk[(i + 8) * 136 + lane]);
            const float mi1 = bf2f(gpk[i * 136 + 64 + lane]) + bf2f(gpk[(i + 8) * 136 + 64 + lane]);
            const float mj0 = bf2f(gpk[j * 136 + lane]) + bf2f(gpk[(j + 8) * 136 + lane]);
            const float mj1 = bf2f(gpk[j * 136 + 64 + lane]) + bf2f(gpk[(j + 8) * 136 + 64 + lane]);
            float v = mi0 * mj0 + mi1 * mj1;
#pragma unroll
            for (int o = 32; o; o >>= 1) v += __shfl_xor(v, o);
            if (lane == 0) Ps[p] = v;
        }
    }
    __syncthreads();
    if (t < 8) {
        float s = 0.f;
#pragma unroll
        for (int w = 0; w < 16; ++w) s += red32[w * 8 + t];
        svals[t] = s;
    }
    __syncthreads();

    // ===== serial scoring =====
    if (t == 0) {
        int idx[8];
        for (int i = 0; i < 8; ++i) idx[i] = i;
        for (int a = 1; a < 8; ++a) {
            const int key = idx[a];
            const float kv = strv[key];
            int bb = a - 1;
            while (bb >= 0 && strv[idx[bb]] < kv) { idx[bb + 1] = idx[bb]; --bb; }
            idx[bb + 1] = key;
        }
        float best = -1e30f;
        int bestk = 2;
        float cons_sum = 0.f, pair_sum = 0.f;
        for (int kk = 1; kk <= 8; ++kk) {
            const int ni = idx[kk - 1];
            cons_sum += svals[ni];
            for (int a = 0; a < kk - 1; ++a) {
                const int ia = idx[a];
                const int lo = ia < ni ? ia : ni;
                const int hi2 = ia < ni ? ni : ia;
                const int off0 = lo * 7 - lo * (lo - 1) / 2;
                pair_sum += Ps[off0 + hi2 - lo - 1];
            }
            if (kk >= 2) {
                const float cons = cons_sum / (kk * 256.0f);
                const float divv = 1.0f - (2.0f / (kk * (kk - 1))) * pair_sum;
                const float score = 0.5f * cons + 0.5f * divv;
                out[256 + b * 7 + (kk - 2)] = score;
                if (score > best) { best = score; bestk = kk; }
            }
        }
        out[b] = (float)bestk;
    }
}

// ---------------------------------------------------------------------------
extern "C" void kernel_launch(void* const* d_in, const int* in_sizes, int n_in,
                              void* d_out, int out_size, void* d_ws, size_t ws_size,
                              hipStream_t stream) {
    const float* e = (const float*)d_in[0];
    const float* W = (const float*)d_in[1];
    const float* b_init = (const float*)d_in[2];
    float* out = (float*)d_out;

    short* whi = (short*)d_ws;
    short* wlo = whi + 16384;
    short* wthi = wlo + 16384;
    short* wtlo = wthi + 16384;

    hipLaunchKernelGGL(setup_w_kernel, dim3(64), dim3(256), 0, stream, W, whi, wlo, wthi, wtlo);
    hipLaunchKernelGGL(fused_kernel, dim3(NB), dim3(1024), 0, stream,
                       e, b_init, whi, wlo, wthi, wtlo, out);
}